// Round 14
// baseline (429.685 us; speedup 1.0000x reference)
//
#include <hip/hip_runtime.h>
#include <hip/hip_bf16.h>

#define NN 10000
#define NE 320000
#define CAP 96   // deg ~ Binom(320000,1e-4): mean 32, sd 5.66; P(overflow) < 1e-19

typedef __attribute__((ext_vector_type(8)))  __bf16 bf16x8;
typedef __attribute__((ext_vector_type(16))) float  f32x16;
typedef __attribute__((ext_vector_type(4)))  float  f32x4;

// ======================= bucket scatter =======================
__global__ void scatter_bucket_kernel(const int* __restrict__ eidx,
                                      int* __restrict__ cnt, int2* __restrict__ bucket) {
    for (int e = blockIdx.x * 256 + threadIdx.x; e < NE; e += gridDim.x * 256) {
        int d = eidx[NE + e];
        int s = eidx[e];
        int p = atomicAdd(&cnt[d], 1);
        if (p < CAP) bucket[d * CAP + p] = make_int2(e, s);
    }
}

// ======================= node-centric fused edge kernel, 2 streams/wave =======================
// Each wave owns TWO dst nodes (n0 = blk*8+w, n1 = blk*8+4+w). Per 32-edge
// chunk and per channel-group g: ONE LDS af read + ONE ci read feed TWO
// independent MFMAs (stream 0/1) -> two dependency-free chains between
// sched_barriers. This attacks the r7-r13 plateau (VALUBusy ~50% at every
// occupancy): per-wave ILP instead of more waves.
//
// SPILL TRAP (r5/r6, 0.7-2.7 GB scratch): opaque base per chunk so af/ci LDS
// reads can't be hoisted chunk-invariantly; sched_barrier(0) per group caps
// liveness at 2 acc tiles (one per stream).
// LDS 37.9KB -> 4 blocks/CU; root/bias read from global in epilogue (L2).
__global__ __launch_bounds__(256, 4) void edge_node_kernel(
    const float* __restrict__ x, const float* __restrict__ ea,
    const float* __restrict__ W, const float* __restrict__ be,
    const float* __restrict__ root, const float* __restrict__ bias,
    const int* __restrict__ cnt, const int2* __restrict__ bucket,
    float* __restrict__ out)
{
    __shared__ __attribute__((aligned(16))) __bf16 WT[32][2][32][8];  // 32 KiB
    __shared__ __attribute__((aligned(16))) float  BPF[32][2][16];    // 4 KiB
    __shared__ float msum[8][32];                                     // 1 KiB

    const int tid = threadIdx.x;

    #pragma unroll
    for (int k = 0; k < 8; ++k) {
        int idx = tid + k * 256;              // (cb, hi, c)
        int cb = idx >> 6, rem = idx & 63, hi2 = rem >> 5, c = rem & 31;
        int cg = cb * 32 + c;
        #pragma unroll
        for (int j = 0; j < 8; ++j)
            WT[cb][hi2][c][j] = (__bf16)W[(8 * hi2 + j) * 1024 + cg];
    }
    #pragma unroll
    for (int k = 0; k < 4; ++k) {
        int idx = tid + k * 256;              // (cb, hi, r)
        int cb = idx >> 5, rem = idx & 31, hi2 = rem >> 4, r = rem & 15;
        int row = (r & 3) + 8 * (r >> 2) + 4 * hi2;
        BPF[cb][hi2][r] = be[cb * 32 + row];
    }
    __syncthreads();

    const int lane = tid & 63;
    const int hi   = lane >> 5;
    const int l31  = lane & 31;
    const int w    = tid >> 6;
    const int n0   = blockIdx.x * 8 + w;       // exact: gridDim.x = NN/8
    const int n1   = n0 + 4;

    const int deg0 = cnt[n0], deg1 = cnt[n1];
    const int degmax = max(deg0, deg1);
    const int2* bk0 = bucket + (size_t)n0 * CAP;
    const int2* bk1 = bucket + (size_t)n1 * CAP;

    float msgr0[16], msgr1[16];
    #pragma unroll
    for (int r = 0; r < 16; ++r) { msgr0[r] = 0.0f; msgr1[r] = 0.0f; }

    for (int c0 = 0; c0 < degmax; c0 += 32) {
        const int idx = c0 + l31;
        const bool a0 = idx < deg0, a1 = idx < deg1;
        const int2 es0 = bk0[a0 ? idx : (deg0 > 0 ? deg0 - 1 : 0)];
        const int2 es1 = bk1[a1 ? idx : (deg1 > 0 ? deg1 - 1 : 0)];

        const f32x4* ep0 = (const f32x4*)(ea + (size_t)es0.x * 16 + hi * 8);
        const f32x4* ep1 = (const f32x4*)(ea + (size_t)es1.x * 16 + hi * 8);
        f32x4 u0 = ep0[0], u1 = ep0[1], v0 = ep1[0], v1 = ep1[1];
        bf16x8 bf0, bf1;
        bf0[0]=(__bf16)u0.x; bf0[1]=(__bf16)u0.y; bf0[2]=(__bf16)u0.z; bf0[3]=(__bf16)u0.w;
        bf0[4]=(__bf16)u1.x; bf0[5]=(__bf16)u1.y; bf0[6]=(__bf16)u1.z; bf0[7]=(__bf16)u1.w;
        bf1[0]=(__bf16)v0.x; bf1[1]=(__bf16)v0.y; bf1[2]=(__bf16)v0.z; bf1[3]=(__bf16)v0.w;
        bf1[4]=(__bf16)v1.x; bf1[5]=(__bf16)v1.y; bf1[6]=(__bf16)v1.z; bf1[7]=(__bf16)v1.w;

        const float4* xp0 = (const float4*)(x + (size_t)es0.y * 32);
        const float4* xp1 = (const float4*)(x + (size_t)es1.y * 32);

        // opaque base: defeats LICM/CSE of the af/ci reads across chunks.
        int base = 0;
        asm volatile("" : "+v"(base));

        #pragma unroll
        for (int cbq = 0; cbq < 8; ++cbq) {
            float4 xq0 = xp0[cbq];
            float4 xq1 = xp1[cbq];
            if (!a0) { xq0.x = 0.f; xq0.y = 0.f; xq0.z = 0.f; xq0.w = 0.f; }
            if (!a1) { xq1.x = 0.f; xq1.y = 0.f; xq1.z = 0.f; xq1.w = 0.f; }
            #pragma unroll
            for (int c4 = 0; c4 < 4; ++c4) {
                const int g = cbq * 4 + c4;
                bf16x8 af = *(const bf16x8*)(&WT[base + g][hi][l31][0]);
                f32x16 ci = *(const f32x16*)(&BPF[base + g][hi][0]);
                f32x16 A0 = __builtin_amdgcn_mfma_f32_32x32x16_bf16(af, bf0, ci, 0, 0, 0);
                f32x16 A1 = __builtin_amdgcn_mfma_f32_32x32x16_bf16(af, bf1, ci, 0, 0, 0);
                const float xv0 = (c4 == 0) ? xq0.x : (c4 == 1) ? xq0.y : (c4 == 2) ? xq0.z : xq0.w;
                const float xv1 = (c4 == 0) ? xq1.x : (c4 == 1) ? xq1.y : (c4 == 2) ? xq1.z : xq1.w;
                #pragma unroll
                for (int r = 0; r < 16; ++r) {
                    msgr0[r] += fmaxf(A0[r], 0.0f) * xv0;
                    msgr1[r] += fmaxf(A1[r], 0.0f) * xv1;
                }
                __builtin_amdgcn_sched_barrier(0);   // 2 independent chains per window
            }
        }
    }

    // reduce across the 32 slot-lanes within each hi-half
    #pragma unroll
    for (int m = 1; m <= 16; m <<= 1) {
        #pragma unroll
        for (int r = 0; r < 16; ++r) {
            msgr0[r] += __shfl_xor(msgr0[r], m, 64);
            msgr1[r] += __shfl_xor(msgr1[r], m, 64);
        }
    }

    const float rd0 = (deg0 > 0) ? (1.0f / (float)deg0) : 0.0f;
    const float rd1 = (deg1 > 0) ? (1.0f / (float)deg1) : 0.0f;
    if (l31 == 0) {
        #pragma unroll
        for (int r = 0; r < 16; ++r) {
            const int o = (r & 3) + 8 * (r >> 2) + 4 * hi;
            msum[w][o]     = msgr0[r] * rd0;
            msum[4 + w][o] = msgr1[r] * rd1;
        }
    }
    __syncthreads();

    // epilogue: 8 rows x 32 ch; row r <-> node blk*8 + r <-> msum[r]
    {
        const int row = tid >> 5, o = tid & 31;
        const int nn  = blockIdx.x * 8 + row;
        const float xv = x[(size_t)nn * 32 + o];   // lane o holds x[nn][o]
        float m = msum[row][o] + bias[o];
        #pragma unroll
        for (int i = 0; i < 32; ++i)
            m += __shfl(xv, i, 32) * root[i * 32 + o];
        out[(size_t)nn * 32 + o] = m;
    }
}

// ======================= launch =======================
extern "C" void kernel_launch(void* const* d_in, const int* in_sizes, int n_in,
                              void* d_out, int out_size, void* d_ws, size_t ws_size,
                              hipStream_t stream) {
    const float* x    = (const float*)d_in[0];
    const int*   eidx = (const int*)d_in[1];     // [2][NE]
    const float* ea   = (const float*)d_in[2];   // [NE][16]
    const float* W    = (const float*)d_in[3];   // [16][1024]
    const float* be   = (const float*)d_in[4];   // [1024]
    const float* root = (const float*)d_in[5];   // [32][32]
    const float* bias = (const float*)d_in[6];   // [32]
    float* out = (float*)d_out;

    // ws: cnt[NN] ints | bucket int2[NN*CAP]
    int*  cnt    = (int*)d_ws;
    int2* bucket = (int2*)((char*)d_ws + ((NN * 4 + 15) & ~15));

    hipMemsetAsync(cnt, 0, NN * sizeof(int), stream);
    scatter_bucket_kernel<<<640, 256, 0, stream>>>(eidx, cnt, bucket);
    edge_node_kernel<<<NN / 8, 256, 0, stream>>>(x, ea, W, be, root, bias,
                                                 cnt, bucket, out);
}

// Round 15
// 104.623 us; speedup vs baseline: 4.1070x; 4.1070x over previous
//
#include <hip/hip_runtime.h>
#include <hip/hip_bf16.h>

#define NN 10000
#define NE 320000
#define CAP 96   // deg ~ Binom(320000,1e-4): mean 32, sd 5.66; P(overflow) < 1e-19

typedef __attribute__((ext_vector_type(8)))  __bf16 bf16x8;
typedef __attribute__((ext_vector_type(16))) float  f32x16;
typedef __attribute__((ext_vector_type(4)))  float  f32x4;

// ======================= bucket scatter =======================
__global__ void scatter_bucket_kernel(const int* __restrict__ eidx,
                                      int* __restrict__ cnt, int2* __restrict__ bucket) {
    for (int e = blockIdx.x * 256 + threadIdx.x; e < NE; e += gridDim.x * 256) {
        int d = eidx[NE + e];
        int s = eidx[e];
        int p = atomicAdd(&cnt[d], 1);
        if (p < CAP) bucket[d * CAP + p] = make_int2(e, s);
    }
}

// ======================= node-centric fused edge kernel, 2 streams/wave =======================
// Each wave owns TWO dst nodes. Per 32-edge chunk and channel-group g: ONE
// LDS af read + ONE ci read feed TWO independent MFMAs -> 2 dependency-free
// chains between sched_barriers (per-wave ILP vs the r7-r13 50%-VALUBusy
// latency plateau).
//
// VGPR BUDGET (r14 lesson): liveness ~110 regs (2x msgr[16] + 2 acc tiles +
// 2 B-frags + addr). __launch_bounds__(256,4) capped at 64 -> 919 MB scratch
// spill, 450us. (256,2) = 128-reg budget fits with margin; ILP substitutes
// for the lost TLP.
// SPILL TRAP (r5/r6): opaque base per chunk so af/ci LDS reads can't be
// hoisted chunk-invariantly; sched_barrier(0) per group caps liveness.
__global__ __launch_bounds__(256, 2) void edge_node_kernel(
    const float* __restrict__ x, const float* __restrict__ ea,
    const float* __restrict__ W, const float* __restrict__ be,
    const float* __restrict__ root, const float* __restrict__ bias,
    const int* __restrict__ cnt, const int2* __restrict__ bucket,
    float* __restrict__ out)
{
    __shared__ __attribute__((aligned(16))) __bf16 WT[32][2][32][8];  // 32 KiB
    __shared__ __attribute__((aligned(16))) float  BPF[32][2][16];    // 4 KiB
    __shared__ float msum[8][32];                                     // 1 KiB

    const int tid = threadIdx.x;

    #pragma unroll
    for (int k = 0; k < 8; ++k) {
        int idx = tid + k * 256;              // (cb, hi, c)
        int cb = idx >> 6, rem = idx & 63, hi2 = rem >> 5, c = rem & 31;
        int cg = cb * 32 + c;
        #pragma unroll
        for (int j = 0; j < 8; ++j)
            WT[cb][hi2][c][j] = (__bf16)W[(8 * hi2 + j) * 1024 + cg];
    }
    #pragma unroll
    for (int k = 0; k < 4; ++k) {
        int idx = tid + k * 256;              // (cb, hi, r)
        int cb = idx >> 5, rem = idx & 31, hi2 = rem >> 4, r = rem & 15;
        int row = (r & 3) + 8 * (r >> 2) + 4 * hi2;
        BPF[cb][hi2][r] = be[cb * 32 + row];
    }
    __syncthreads();

    const int lane = tid & 63;
    const int hi   = lane >> 5;
    const int l31  = lane & 31;
    const int w    = tid >> 6;
    const int n0   = blockIdx.x * 8 + w;       // exact: gridDim.x = NN/8
    const int n1   = n0 + 4;

    const int deg0 = cnt[n0], deg1 = cnt[n1];
    const int degmax = max(deg0, deg1);
    const int2* bk0 = bucket + (size_t)n0 * CAP;
    const int2* bk1 = bucket + (size_t)n1 * CAP;

    float msgr0[16], msgr1[16];
    #pragma unroll
    for (int r = 0; r < 16; ++r) { msgr0[r] = 0.0f; msgr1[r] = 0.0f; }

    for (int c0 = 0; c0 < degmax; c0 += 32) {
        const int idx = c0 + l31;
        const bool a0 = idx < deg0, a1 = idx < deg1;
        const int2 es0 = bk0[a0 ? idx : (deg0 > 0 ? deg0 - 1 : 0)];
        const int2 es1 = bk1[a1 ? idx : (deg1 > 0 ? deg1 - 1 : 0)];

        const f32x4* ep0 = (const f32x4*)(ea + (size_t)es0.x * 16 + hi * 8);
        const f32x4* ep1 = (const f32x4*)(ea + (size_t)es1.x * 16 + hi * 8);
        f32x4 u0 = ep0[0], u1 = ep0[1], v0 = ep1[0], v1 = ep1[1];
        bf16x8 bf0, bf1;
        bf0[0]=(__bf16)u0.x; bf0[1]=(__bf16)u0.y; bf0[2]=(__bf16)u0.z; bf0[3]=(__bf16)u0.w;
        bf0[4]=(__bf16)u1.x; bf0[5]=(__bf16)u1.y; bf0[6]=(__bf16)u1.z; bf0[7]=(__bf16)u1.w;
        bf1[0]=(__bf16)v0.x; bf1[1]=(__bf16)v0.y; bf1[2]=(__bf16)v0.z; bf1[3]=(__bf16)v0.w;
        bf1[4]=(__bf16)v1.x; bf1[5]=(__bf16)v1.y; bf1[6]=(__bf16)v1.z; bf1[7]=(__bf16)v1.w;

        const float4* xp0 = (const float4*)(x + (size_t)es0.y * 32);
        const float4* xp1 = (const float4*)(x + (size_t)es1.y * 32);

        // opaque base: defeats LICM/CSE of the af/ci reads across chunks.
        int base = 0;
        asm volatile("" : "+v"(base));

        #pragma unroll
        for (int cbq = 0; cbq < 8; ++cbq) {
            float4 xq0 = xp0[cbq];
            float4 xq1 = xp1[cbq];
            if (!a0) { xq0.x = 0.f; xq0.y = 0.f; xq0.z = 0.f; xq0.w = 0.f; }
            if (!a1) { xq1.x = 0.f; xq1.y = 0.f; xq1.z = 0.f; xq1.w = 0.f; }
            #pragma unroll
            for (int c4 = 0; c4 < 4; ++c4) {
                const int g = cbq * 4 + c4;
                bf16x8 af = *(const bf16x8*)(&WT[base + g][hi][l31][0]);
                f32x16 ci = *(const f32x16*)(&BPF[base + g][hi][0]);
                f32x16 A0 = __builtin_amdgcn_mfma_f32_32x32x16_bf16(af, bf0, ci, 0, 0, 0);
                f32x16 A1 = __builtin_amdgcn_mfma_f32_32x32x16_bf16(af, bf1, ci, 0, 0, 0);
                const float xv0 = (c4 == 0) ? xq0.x : (c4 == 1) ? xq0.y : (c4 == 2) ? xq0.z : xq0.w;
                const float xv1 = (c4 == 0) ? xq1.x : (c4 == 1) ? xq1.y : (c4 == 2) ? xq1.z : xq1.w;
                #pragma unroll
                for (int r = 0; r < 16; ++r) {
                    msgr0[r] += fmaxf(A0[r], 0.0f) * xv0;
                    msgr1[r] += fmaxf(A1[r], 0.0f) * xv1;
                }
                __builtin_amdgcn_sched_barrier(0);   // 2 independent chains per window
            }
        }
    }

    // reduce across the 32 slot-lanes within each hi-half
    #pragma unroll
    for (int m = 1; m <= 16; m <<= 1) {
        #pragma unroll
        for (int r = 0; r < 16; ++r) {
            msgr0[r] += __shfl_xor(msgr0[r], m, 64);
            msgr1[r] += __shfl_xor(msgr1[r], m, 64);
        }
    }

    const float rd0 = (deg0 > 0) ? (1.0f / (float)deg0) : 0.0f;
    const float rd1 = (deg1 > 0) ? (1.0f / (float)deg1) : 0.0f;
    if (l31 == 0) {
        #pragma unroll
        for (int r = 0; r < 16; ++r) {
            const int o = (r & 3) + 8 * (r >> 2) + 4 * hi;
            msum[w][o]     = msgr0[r] * rd0;
            msum[4 + w][o] = msgr1[r] * rd1;
        }
    }
    __syncthreads();

    // epilogue: 8 rows x 32 ch; row r <-> node blk*8 + r <-> msum[r]
    {
        const int row = tid >> 5, o = tid & 31;
        const int nn  = blockIdx.x * 8 + row;
        const float xv = x[(size_t)nn * 32 + o];   // lane o holds x[nn][o]
        float m = msum[row][o] + bias[o];
        #pragma unroll
        for (int i = 0; i < 32; ++i)
            m += __shfl(xv, i, 32) * root[i * 32 + o];
        out[(size_t)nn * 32 + o] = m;
    }
}

// ======================= launch =======================
extern "C" void kernel_launch(void* const* d_in, const int* in_sizes, int n_in,
                              void* d_out, int out_size, void* d_ws, size_t ws_size,
                              hipStream_t stream) {
    const float* x    = (const float*)d_in[0];
    const int*   eidx = (const int*)d_in[1];     // [2][NE]
    const float* ea   = (const float*)d_in[2];   // [NE][16]
    const float* W    = (const float*)d_in[3];   // [16][1024]
    const float* be   = (const float*)d_in[4];   // [1024]
    const float* root = (const float*)d_in[5];   // [32][32]
    const float* bias = (const float*)d_in[6];   // [32]
    float* out = (float*)d_out;

    // ws: cnt[NN] ints | bucket int2[NN*CAP]
    int*  cnt    = (int*)d_ws;
    int2* bucket = (int2*)((char*)d_ws + ((NN * 4 + 15) & ~15));

    hipMemsetAsync(cnt, 0, NN * sizeof(int), stream);
    scatter_bucket_kernel<<<640, 256, 0, stream>>>(eidx, cnt, bucket);
    edge_node_kernel<<<NN / 8, 256, 0, stream>>>(x, ea, W, be, root, bias,
                                                 cnt, bucket, out);
}